// Round 3
// baseline (199.864 us; speedup 1.0000x reference)
//
#include <hip/hip_runtime.h>
#include <hip/hip_bf16.h>

#define C 32
#define R 8

// ---- M[r][c][j] = sum_o W_tp[c][r][o] * W1[r*C+o][j]   (f32, 32 KB) ----
__global__ void k_prepM(const float* __restrict__ Wtp, const float* __restrict__ W1,
                        float* __restrict__ M) {
    int idx = blockIdx.x * 256 + threadIdx.x;
    if (idx >= R * C * C) return;
    int r = idx >> 10;
    int c = (idx >> 5) & 31;
    int j = idx & 31;
    float acc = 0.f;
#pragma unroll
    for (int o = 0; o < C; ++o)
        acc = fmaf(Wtp[c * R * C + r * C + o], W1[(r * C + o) * C + j], acc);
    M[idx] = acc;
}

// ---- z[n][j][r] = sum_c x[n][c] * M[r][c][j]  (f32; r contiguous) ----
// thread t: j = t>>3, r = t&7  => z index n*256 + t  (contiguous stores)
__global__ void k_nodeZ(const float* __restrict__ x, const float* __restrict__ M,
                        float* __restrict__ z, int N, int npb) {
    int t = threadIdx.x;
    int r = t & 7, j = t >> 3;
    float m[C];
#pragma unroll
    for (int c = 0; c < C; ++c) m[c] = M[r * C * C + c * C + j];
    int n0 = blockIdx.x * npb;
    int n1 = n0 + npb;
    if (n1 > N) n1 = N;
    for (int n = n0; n < n1; ++n) {
        const float* xp = x + (size_t)n * C;
        float acc = 0.f;
#pragma unroll
        for (int c = 0; c < C; ++c) acc = fmaf(xp[c], m[c], acc);
        z[(size_t)n * (R * C) + t] = acc;
    }
}

// rbf: centers = linspace(0,5,8), width = 5/7, scaling = 1/sqrt(2pi)
__device__ __forceinline__ float rbf_lane(float dist, int r) {
    float t = (dist - 0.71428573f * (float)r) * 1.3999999f;
    return 0.3989423f * expf(-0.5f * t * t);
}

// ---- per edge (32 lanes): h[j] = b1[j] + sum_r rbf[r]*z[col][j][r]; agg[row]+=silu(h)
__global__ void k_edge(const int* __restrict__ ei, const float* __restrict__ pos,
                       const float* __restrict__ z, const float* __restrict__ b1,
                       float* __restrict__ agg, float* __restrict__ deg,
                       int E, int N) {
    int gt = blockIdx.x * blockDim.x + threadIdx.x;
    int j = gt & 31;
    int g = gt >> 5;
    int ngroups = (gridDim.x * blockDim.x) >> 5;
    float b1j = b1[j];
    for (int e = g; e < E; e += ngroups) {
        int row = ei[e];
        int col = ei[E + e];
        row = ((unsigned)row < (unsigned)N) ? row : 0;
        col = ((unsigned)col < (unsigned)N) ? col : 0;
        float dx = pos[row * 3 + 0] - pos[col * 3 + 0];
        float dy = pos[row * 3 + 1] - pos[col * 3 + 1];
        float dz = pos[row * 3 + 2] - pos[col * 3 + 2];
        float dist = sqrtf(fmaf(dx, dx, fmaf(dy, dy, dz * dz)) + 1e-12f);
        float my_rbf = rbf_lane(dist, j & 7);
        const float* zp = z + (size_t)col * (R * C) + j * R;
        float4 v0 = *(const float4*)zp;
        float4 v1 = *(const float4*)(zp + 4);
        float h = b1j;
        h = fmaf(__shfl(my_rbf, 0, 32), v0.x, h);
        h = fmaf(__shfl(my_rbf, 1, 32), v0.y, h);
        h = fmaf(__shfl(my_rbf, 2, 32), v0.z, h);
        h = fmaf(__shfl(my_rbf, 3, 32), v0.w, h);
        h = fmaf(__shfl(my_rbf, 4, 32), v1.x, h);
        h = fmaf(__shfl(my_rbf, 5, 32), v1.y, h);
        h = fmaf(__shfl(my_rbf, 6, 32), v1.z, h);
        h = fmaf(__shfl(my_rbf, 7, 32), v1.w, h);
        float sh = h / (1.f + expf(-h)); // silu
        atomicAdd(&agg[(size_t)row * C + j], sh);
        if (j == 0) atomicAdd(&deg[row], 1.f);
    }
}

// ---- Tier B: direct edge (M from ws, staged to LDS); agg in ws ----
__global__ void k_edge_direct(const int* __restrict__ ei, const float* __restrict__ pos,
                              const float* __restrict__ x, const float* __restrict__ M,
                              const float* __restrict__ b1,
                              float* __restrict__ agg, float* __restrict__ deg,
                              int E, int N) {
    __shared__ float Ms[R * C * C];
    for (int i = threadIdx.x; i < R * C * C; i += blockDim.x) Ms[i] = M[i];
    __syncthreads();
    int gt = blockIdx.x * blockDim.x + threadIdx.x;
    int j = gt & 31;
    int g = gt >> 5;
    int ngroups = (gridDim.x * blockDim.x) >> 5;
    float b1j = b1[j];
    for (int e = g; e < E; e += ngroups) {
        int row = ei[e];
        int col = ei[E + e];
        row = ((unsigned)row < (unsigned)N) ? row : 0;
        col = ((unsigned)col < (unsigned)N) ? col : 0;
        float dx = pos[row * 3 + 0] - pos[col * 3 + 0];
        float dy = pos[row * 3 + 1] - pos[col * 3 + 1];
        float dz = pos[row * 3 + 2] - pos[col * 3 + 2];
        float dist = sqrtf(fmaf(dx, dx, fmaf(dy, dy, dz * dz)) + 1e-12f);
        float my_rbf = rbf_lane(dist, j & 7);
        float xr[C];
#pragma unroll
        for (int c = 0; c < C; ++c) xr[c] = x[(size_t)col * C + c];
        float h = b1j;
#pragma unroll
        for (int r = 0; r < R; ++r) {
            float s = 0.f;
#pragma unroll
            for (int c = 0; c < C; ++c)
                s = fmaf(xr[c], Ms[r * C * C + c * C + j], s);
            h = fmaf(__shfl(my_rbf, r, 32), s, h);
        }
        float sh = h / (1.f + expf(-h));
        atomicAdd(&agg[(size_t)row * C + j], sh);
        if (j == 0) atomicAdd(&deg[row], 1.f);
    }
}

// ---- out[n][j] = x[n][j] + sum_i agg[n][i]*W2[i][j] + deg[n]*b2[j] ----
__global__ void k_final(const float* __restrict__ x, const float* __restrict__ agg,
                        const float* __restrict__ deg, const float* __restrict__ W2,
                        const float* __restrict__ b2, float* __restrict__ out,
                        int N) {
    int t = threadIdx.x;
    int j = t & 31;
    float w2[C];
#pragma unroll
    for (int i = 0; i < C; ++i) w2[i] = W2[i * C + j];
    float b2j = b2[j];
    int g = (blockIdx.x * blockDim.x + t) >> 5;
    int ngroups = (gridDim.x * blockDim.x) >> 5;
    for (int n = g; n < N; n += ngroups) {
        const float* ap = agg + (size_t)n * C;
        float acc = 0.f;
#pragma unroll
        for (int i = 0; i < C; ++i) acc = fmaf(ap[i], w2[i], acc);
        out[(size_t)n * C + j] = x[(size_t)n * C + j] + acc + deg[n] * b2j;
    }
}

// ---- Tier C (no usable ws): everything in LDS, scatter straight into out ----
__global__ void k_edge_full(const int* __restrict__ ei, const float* __restrict__ pos,
                            const float* __restrict__ x,
                            const float* __restrict__ Wtp, const float* __restrict__ W1,
                            const float* __restrict__ b1,
                            const float* __restrict__ W2, const float* __restrict__ b2,
                            float* __restrict__ out, int E, int N) {
    __shared__ float Ms[R * C * C];
    __shared__ float W2s[C * C];
    for (int idx = threadIdx.x; idx < R * C * C; idx += blockDim.x) {
        int r = idx >> 10, c = (idx >> 5) & 31, jj = idx & 31;
        float acc = 0.f;
#pragma unroll
        for (int o = 0; o < C; ++o)
            acc = fmaf(Wtp[c * R * C + r * C + o], W1[(r * C + o) * C + jj], acc);
        Ms[idx] = acc;
    }
    for (int idx = threadIdx.x; idx < C * C; idx += blockDim.x) W2s[idx] = W2[idx];
    __syncthreads();
    int gt = blockIdx.x * blockDim.x + threadIdx.x;
    int j = gt & 31;
    int g = gt >> 5;
    int ngroups = (gridDim.x * blockDim.x) >> 5;
    float b1j = b1[j];
    float b2j = b2[j];
    for (int e = g; e < E; e += ngroups) {
        int row = ei[e];
        int col = ei[E + e];
        row = ((unsigned)row < (unsigned)N) ? row : 0;
        col = ((unsigned)col < (unsigned)N) ? col : 0;
        float dx = pos[row * 3 + 0] - pos[col * 3 + 0];
        float dy = pos[row * 3 + 1] - pos[col * 3 + 1];
        float dz = pos[row * 3 + 2] - pos[col * 3 + 2];
        float dist = sqrtf(fmaf(dx, dx, fmaf(dy, dy, dz * dz)) + 1e-12f);
        float my_rbf = rbf_lane(dist, j & 7);
        float xr[C];
#pragma unroll
        for (int c = 0; c < C; ++c) xr[c] = x[(size_t)col * C + c];
        float h = b1j;
#pragma unroll
        for (int r = 0; r < R; ++r) {
            float s = 0.f;
#pragma unroll
            for (int c = 0; c < C; ++c)
                s = fmaf(xr[c], Ms[r * C * C + c * C + j], s);
            h = fmaf(__shfl(my_rbf, r, 32), s, h);
        }
        float sh = h / (1.f + expf(-h));
        float v = b2j;
#pragma unroll
        for (int i = 0; i < C; ++i)
            v = fmaf(__shfl(sh, i, 32), W2s[i * C + j], v);
        atomicAdd(&out[(size_t)row * C + j], v);
    }
}

__global__ void k_add_x(const float* __restrict__ x, float* __restrict__ out, int total) {
    int i = blockIdx.x * blockDim.x + threadIdx.x;
    int stride = gridDim.x * blockDim.x;
    for (; i < total; i += stride) out[i] += x[i];
}

extern "C" void kernel_launch(void* const* d_in, const int* in_sizes, int n_in,
                              void* d_out, int out_size, void* d_ws, size_t ws_size,
                              hipStream_t stream) {
    const float* x   = (const float*)d_in[0];
    const float* pos = (const float*)d_in[1];
    const int*   ei  = (const int*)d_in[2];
    const float* Wtp = (const float*)d_in[3];
    const float* W1  = (const float*)d_in[4];
    const float* b1  = (const float*)d_in[5];
    const float* W2  = (const float*)d_in[6];
    const float* b2  = (const float*)d_in[7];
    int N = in_sizes[0] / C;
    int E = in_sizes[2] / 2;

    char* ws = (char*)d_ws;
    size_t mBytes   = (size_t)R * C * C * sizeof(float);        // 32 KB
    size_t zBytes   = (size_t)N * R * C * sizeof(float);        // 51.2 MB
    size_t aggBytes = (size_t)N * (C + 1) * sizeof(float);      // 6.6 MB
    bool tierA = ws_size >= mBytes + zBytes + aggBytes;
    bool tierB = !tierA && ws_size >= mBytes + aggBytes;

    if (tierA) {
        float* M   = (float*)ws;
        float* z   = (float*)(ws + mBytes);
        float* agg = (float*)(ws + mBytes + zBytes);
        float* deg = agg + (size_t)N * C;
        hipMemsetAsync(agg, 0, aggBytes, stream);
        k_prepM<<<(R * C * C + 255) / 256, 256, 0, stream>>>(Wtp, W1, M);
        int npb = 32;
        k_nodeZ<<<(N + npb - 1) / npb, 256, 0, stream>>>(x, M, z, N, npb);
        k_edge<<<2048, 256, 0, stream>>>(ei, pos, z, b1, agg, deg, E, N);
        k_final<<<1024, 256, 0, stream>>>(x, agg, deg, W2, b2, (float*)d_out, N);
    } else if (tierB) {
        float* M   = (float*)ws;
        float* agg = (float*)(ws + mBytes);
        float* deg = agg + (size_t)N * C;
        hipMemsetAsync(agg, 0, aggBytes, stream);
        k_prepM<<<(R * C * C + 255) / 256, 256, 0, stream>>>(Wtp, W1, M);
        k_edge_direct<<<2048, 256, 0, stream>>>(ei, pos, x, M, b1, agg, deg, E, N);
        k_final<<<1024, 256, 0, stream>>>(x, agg, deg, W2, b2, (float*)d_out, N);
    } else {
        hipMemsetAsync(d_out, 0, (size_t)N * C * sizeof(float), stream);
        k_edge_full<<<1024, 256, 0, stream>>>(ei, pos, x, Wtp, W1, b1, W2, b2,
                                              (float*)d_out, E, N);
        k_add_x<<<1024, 256, 0, stream>>>(x, (float*)d_out, N * C);
    }
}

// Round 4
// 189.151 us; speedup vs baseline: 1.0566x; 1.0566x over previous
//
#include <hip/hip_runtime.h>
#include <hip/hip_bf16.h>

#define C 32
#define R 8

typedef unsigned int u32;
__device__ __forceinline__ float bflo(u32 u) { return __uint_as_float(u << 16); }
__device__ __forceinline__ float bfhi(u32 u) { return __uint_as_float(u & 0xffff0000u); }

// ---- M[r][c][j] = sum_o W_tp[c][r][o] * W1[r*C+o][j]   (f32, 32 KB) ----
__global__ void k_prepM(const float* __restrict__ Wtp, const float* __restrict__ W1,
                        float* __restrict__ M) {
    int idx = blockIdx.x * 256 + threadIdx.x;
    if (idx >= R * C * C) return;
    int r = idx >> 10;
    int c = (idx >> 5) & 31;
    int j = idx & 31;
    float acc = 0.f;
#pragma unroll
    for (int o = 0; o < C; ++o)
        acc = fmaf(Wtp[c * R * C + r * C + o], W1[(r * C + o) * C + j], acc);
    M[idx] = acc;
}

// ---- z[n][j][r] = sum_c x[n][c] * M[r][c][j]  (bf16; r contiguous) ----
// thread t: j = t>>3, r = t&7  => z index n*256 + t (contiguous 2B stores)
__global__ void k_nodeZ(const float* __restrict__ x, const float* __restrict__ M,
                        __hip_bfloat16* __restrict__ z, int N, int npb) {
    int t = threadIdx.x;
    int r = t & 7, j = t >> 3;
    float m[C];
#pragma unroll
    for (int c = 0; c < C; ++c) m[c] = M[r * C * C + c * C + j];
    int n0 = blockIdx.x * npb;
    int n1 = n0 + npb;
    if (n1 > N) n1 = N;
    for (int n = n0; n < n1; ++n) {
        const float* xp = x + (size_t)n * C;
        float acc = 0.f;
#pragma unroll
        for (int c = 0; c < C; ++c) acc = fmaf(xp[c], m[c], acc);
        z[(size_t)n * (R * C) + t] = __float2bfloat16(acc);
    }
}

// rbf: centers = linspace(0,5,8), width = 5/7, scaling = 1/sqrt(2pi)
__device__ __forceinline__ float rbf_lane(float dist, int r) {
    float t = (dist - 0.71428573f * (float)r) * 1.3999999f;
    return 0.3989423f * __expf(-0.5f * t * t);
}

// ---- per edge (32 lanes): h[j] = b1[j] + sum_r rbf[r]*z[col][j][r]; agg[row]+=silu(h)
__global__ void k_edge(const int* __restrict__ ei, const float* __restrict__ pos,
                       const __hip_bfloat16* __restrict__ z, const float* __restrict__ b1,
                       float* __restrict__ agg, float* __restrict__ deg,
                       int E, int N) {
    int gt = blockIdx.x * blockDim.x + threadIdx.x;
    int j = gt & 31;
    int g = gt >> 5;
    int ngroups = (gridDim.x * blockDim.x) >> 5;
    float b1j = b1[j];
    for (int e = g; e < E; e += ngroups) {
        int row = ei[e];
        int col = ei[E + e];
        row = ((unsigned)row < (unsigned)N) ? row : 0;
        col = ((unsigned)col < (unsigned)N) ? col : 0;
        float dx = pos[row * 3 + 0] - pos[col * 3 + 0];
        float dy = pos[row * 3 + 1] - pos[col * 3 + 1];
        float dz = pos[row * 3 + 2] - pos[col * 3 + 2];
        float dist = sqrtf(fmaf(dx, dx, fmaf(dy, dy, dz * dz)) + 1e-12f);
        float my_rbf = rbf_lane(dist, j & 7);
        uint4 v = ((const uint4*)(z + (size_t)col * (R * C)))[j];
        float h = b1j;
        h = fmaf(__shfl(my_rbf, 0, 32), bflo(v.x), h);
        h = fmaf(__shfl(my_rbf, 1, 32), bfhi(v.x), h);
        h = fmaf(__shfl(my_rbf, 2, 32), bflo(v.y), h);
        h = fmaf(__shfl(my_rbf, 3, 32), bfhi(v.y), h);
        h = fmaf(__shfl(my_rbf, 4, 32), bflo(v.z), h);
        h = fmaf(__shfl(my_rbf, 5, 32), bfhi(v.z), h);
        h = fmaf(__shfl(my_rbf, 6, 32), bflo(v.w), h);
        h = fmaf(__shfl(my_rbf, 7, 32), bfhi(v.w), h);
        float sh = h / (1.f + __expf(-h)); // silu
        atomicAdd(&agg[(size_t)row * C + j], sh);
        if (j == 0) atomicAdd(&deg[row], 1.f);
    }
}

// ---- Tier B: direct edge (M from ws, staged to LDS); agg in ws ----
__global__ void k_edge_direct(const int* __restrict__ ei, const float* __restrict__ pos,
                              const float* __restrict__ x, const float* __restrict__ M,
                              const float* __restrict__ b1,
                              float* __restrict__ agg, float* __restrict__ deg,
                              int E, int N) {
    __shared__ float Ms[R * C * C];
    for (int i = threadIdx.x; i < R * C * C; i += blockDim.x) Ms[i] = M[i];
    __syncthreads();
    int gt = blockIdx.x * blockDim.x + threadIdx.x;
    int j = gt & 31;
    int g = gt >> 5;
    int ngroups = (gridDim.x * blockDim.x) >> 5;
    float b1j = b1[j];
    for (int e = g; e < E; e += ngroups) {
        int row = ei[e];
        int col = ei[E + e];
        row = ((unsigned)row < (unsigned)N) ? row : 0;
        col = ((unsigned)col < (unsigned)N) ? col : 0;
        float dx = pos[row * 3 + 0] - pos[col * 3 + 0];
        float dy = pos[row * 3 + 1] - pos[col * 3 + 1];
        float dz = pos[row * 3 + 2] - pos[col * 3 + 2];
        float dist = sqrtf(fmaf(dx, dx, fmaf(dy, dy, dz * dz)) + 1e-12f);
        float my_rbf = rbf_lane(dist, j & 7);
        float xr[C];
#pragma unroll
        for (int c = 0; c < C; ++c) xr[c] = x[(size_t)col * C + c];
        float h = b1j;
#pragma unroll
        for (int r = 0; r < R; ++r) {
            float s = 0.f;
#pragma unroll
            for (int c = 0; c < C; ++c)
                s = fmaf(xr[c], Ms[r * C * C + c * C + j], s);
            h = fmaf(__shfl(my_rbf, r, 32), s, h);
        }
        float sh = h / (1.f + __expf(-h));
        atomicAdd(&agg[(size_t)row * C + j], sh);
        if (j == 0) atomicAdd(&deg[row], 1.f);
    }
}

// ---- out[n][j] = x[n][j] + sum_i agg[n][i]*W2[i][j] + deg[n]*b2[j] ----
__global__ void k_final(const float* __restrict__ x, const float* __restrict__ agg,
                        const float* __restrict__ deg, const float* __restrict__ W2,
                        const float* __restrict__ b2, float* __restrict__ out,
                        int N) {
    int t = threadIdx.x;
    int j = t & 31;
    float w2[C];
#pragma unroll
    for (int i = 0; i < C; ++i) w2[i] = W2[i * C + j];
    float b2j = b2[j];
    int g = (blockIdx.x * blockDim.x + t) >> 5;
    int ngroups = (gridDim.x * blockDim.x) >> 5;
    for (int n = g; n < N; n += ngroups) {
        const float* ap = agg + (size_t)n * C;
        float acc = 0.f;
#pragma unroll
        for (int i = 0; i < C; ++i) acc = fmaf(ap[i], w2[i], acc);
        out[(size_t)n * C + j] = x[(size_t)n * C + j] + acc + deg[n] * b2j;
    }
}

// ---- Tier C (no usable ws): everything in LDS, scatter straight into out ----
__global__ void k_edge_full(const int* __restrict__ ei, const float* __restrict__ pos,
                            const float* __restrict__ x,
                            const float* __restrict__ Wtp, const float* __restrict__ W1,
                            const float* __restrict__ b1,
                            const float* __restrict__ W2, const float* __restrict__ b2,
                            float* __restrict__ out, int E, int N) {
    __shared__ float Ms[R * C * C];
    __shared__ float W2s[C * C];
    for (int idx = threadIdx.x; idx < R * C * C; idx += blockDim.x) {
        int r = idx >> 10, c = (idx >> 5) & 31, jj = idx & 31;
        float acc = 0.f;
#pragma unroll
        for (int o = 0; o < C; ++o)
            acc = fmaf(Wtp[c * R * C + r * C + o], W1[(r * C + o) * C + jj], acc);
        Ms[idx] = acc;
    }
    for (int idx = threadIdx.x; idx < C * C; idx += blockDim.x) W2s[idx] = W2[idx];
    __syncthreads();
    int gt = blockIdx.x * blockDim.x + threadIdx.x;
    int j = gt & 31;
    int g = gt >> 5;
    int ngroups = (gridDim.x * blockDim.x) >> 5;
    float b1j = b1[j];
    float b2j = b2[j];
    for (int e = g; e < E; e += ngroups) {
        int row = ei[e];
        int col = ei[E + e];
        row = ((unsigned)row < (unsigned)N) ? row : 0;
        col = ((unsigned)col < (unsigned)N) ? col : 0;
        float dx = pos[row * 3 + 0] - pos[col * 3 + 0];
        float dy = pos[row * 3 + 1] - pos[col * 3 + 1];
        float dz = pos[row * 3 + 2] - pos[col * 3 + 2];
        float dist = sqrtf(fmaf(dx, dx, fmaf(dy, dy, dz * dz)) + 1e-12f);
        float my_rbf = rbf_lane(dist, j & 7);
        float xr[C];
#pragma unroll
        for (int c = 0; c < C; ++c) xr[c] = x[(size_t)col * C + c];
        float h = b1j;
#pragma unroll
        for (int r = 0; r < R; ++r) {
            float s = 0.f;
#pragma unroll
            for (int c = 0; c < C; ++c)
                s = fmaf(xr[c], Ms[r * C * C + c * C + j], s);
            h = fmaf(__shfl(my_rbf, r, 32), s, h);
        }
        float sh = h / (1.f + __expf(-h));
        float v = b2j;
#pragma unroll
        for (int i = 0; i < C; ++i)
            v = fmaf(__shfl(sh, i, 32), W2s[i * C + j], v);
        atomicAdd(&out[(size_t)row * C + j], v);
    }
}

__global__ void k_add_x(const float* __restrict__ x, float* __restrict__ out, int total) {
    int i = blockIdx.x * blockDim.x + threadIdx.x;
    int stride = gridDim.x * blockDim.x;
    for (; i < total; i += stride) out[i] += x[i];
}

extern "C" void kernel_launch(void* const* d_in, const int* in_sizes, int n_in,
                              void* d_out, int out_size, void* d_ws, size_t ws_size,
                              hipStream_t stream) {
    const float* x   = (const float*)d_in[0];
    const float* pos = (const float*)d_in[1];
    const int*   ei  = (const int*)d_in[2];
    const float* Wtp = (const float*)d_in[3];
    const float* W1  = (const float*)d_in[4];
    const float* b1  = (const float*)d_in[5];
    const float* W2  = (const float*)d_in[6];
    const float* b2  = (const float*)d_in[7];
    int N = in_sizes[0] / C;
    int E = in_sizes[2] / 2;

    char* ws = (char*)d_ws;
    size_t mBytes   = (size_t)R * C * C * sizeof(float);              // 32 KB
    size_t zBytes   = (size_t)N * R * C * sizeof(__hip_bfloat16);     // 25.6 MB
    size_t aggBytes = (size_t)N * (C + 1) * sizeof(float);            // 6.6 MB
    bool tierA = ws_size >= mBytes + zBytes + aggBytes;
    bool tierB = !tierA && ws_size >= mBytes + aggBytes;

    if (tierA) {
        float*          M   = (float*)ws;
        __hip_bfloat16* z   = (__hip_bfloat16*)(ws + mBytes);
        float*          agg = (float*)(ws + mBytes + zBytes);
        float*          deg = agg + (size_t)N * C;
        hipMemsetAsync(agg, 0, aggBytes, stream);
        k_prepM<<<(R * C * C + 255) / 256, 256, 0, stream>>>(Wtp, W1, M);
        int npb = 32;
        k_nodeZ<<<(N + npb - 1) / npb, 256, 0, stream>>>(x, M, z, N, npb);
        k_edge<<<2048, 256, 0, stream>>>(ei, pos, z, b1, agg, deg, E, N);
        k_final<<<1024, 256, 0, stream>>>(x, agg, deg, W2, b2, (float*)d_out, N);
    } else if (tierB) {
        float* M   = (float*)ws;
        float* agg = (float*)(ws + mBytes);
        float* deg = agg + (size_t)N * C;
        hipMemsetAsync(agg, 0, aggBytes, stream);
        k_prepM<<<(R * C * C + 255) / 256, 256, 0, stream>>>(Wtp, W1, M);
        k_edge_direct<<<2048, 256, 0, stream>>>(ei, pos, x, M, b1, agg, deg, E, N);
        k_final<<<1024, 256, 0, stream>>>(x, agg, deg, W2, b2, (float*)d_out, N);
    } else {
        hipMemsetAsync(d_out, 0, (size_t)N * C * sizeof(float), stream);
        k_edge_full<<<1024, 256, 0, stream>>>(ei, pos, x, Wtp, W1, b1, W2, b2,
                                              (float*)d_out, E, N);
        k_add_x<<<1024, 256, 0, stream>>>(x, (float*)d_out, N * C);
    }
}